// Round 1
// baseline (1827.340 us; speedup 1.0000x reference)
//
#include <hip/hip_runtime.h>
#include <hip/hip_bf16.h>
#include <cstddef>
#include <cstdint>

// Problem constants
// B=16, DIM=256, H=W=80, C=64 per branch, HEADS=8, DH=8, n=6400
// Workspace layout (float offsets):
static constexpr size_t OFF_Y    = 0;                    // [b][256][6400]           (104.86 MB)
static constexpr size_t OFF_QEXP = 26214400;             // [i][b][h][t][e]          (104.86 MB)
static constexpr size_t OFF_CTX  = 52428800;             // [i*16+b][h][ke][vd]      (32768)
static constexpr size_t OFF_QS   = 52461568;             // [i*16+b][h][e]           (4096)
static constexpr size_t OFF_CTXN = 52465664;             // normalized ctx           (32768)
static constexpr size_t OFF_WC   = 52498432;             // combined weight [256][256]
static constexpr size_t OFF_BC   = 52563968;             // combined bias [256]

// ---------------------------------------------------------------------------
// Kernel A: fold wproj/scale/wf/bproj/bf into combined Wc[256][256], bc[256]
//   Wc[o][i*64+c'] = scale[i] * sum_cc wf[o, i*64+cc] * wproj[cc, c']
//   bc[o] = bf[o] + sum_i scale[i] * sum_cc wf[o,i*64+cc] * bproj[cc]
__global__ void combine_w(const float* __restrict__ wf, const float* __restrict__ wproj,
                          const float* __restrict__ bproj, const float* __restrict__ bf,
                          const float* __restrict__ scale,
                          float* __restrict__ Wc, float* __restrict__ bc) {
    int o  = blockIdx.x;     // 256
    int cp = threadIdx.x;    // 64
    for (int i = 0; i < 4; i++) {
        float s = 0.f;
        for (int cc = 0; cc < 64; cc++)
            s = fmaf(wf[o*256 + i*64 + cc], wproj[cc*64 + cp], s);
        Wc[o*256 + i*64 + cp] = scale[i] * s;
    }
    if (cp == 0) {
        float s = bf[o];
        for (int i = 0; i < 4; i++) {
            float t = 0.f;
            for (int cc = 0; cc < 64; cc++)
                t = fmaf(wf[o*256 + i*64 + cc], bproj[cc], t);
            s = fmaf(scale[i], t, s);
        }
        bc[o] = s;
    }
}

// ---------------------------------------------------------------------------
// Kernel B: depthwise conv KxK SAME + bias + residual + relu (templated on K)
// One block per (b, c) plane of branch `br`. 88x88 LDS tile (halo 4, zero-pad).
template<int K>
__global__ __launch_bounds__(256) void dwconv_k(const float* __restrict__ x,
    const float* __restrict__ w, const float* __restrict__ bias,
    float* __restrict__ y, int br) {
    __shared__ float tile[88*88];
    int b = blockIdx.x >> 6;
    int c = blockIdx.x & 63;
    int ch = br*64 + c;
    const float* xp = x + ((size_t)b*256 + ch) * 6400;
    for (int p = threadIdx.x; p < 88*88; p += 256) {
        int ty = p / 88, tx = p - (p/88)*88;
        int sy = ty - 4, sx = tx - 4;
        tile[p] = (sy >= 0 && sy < 80 && sx >= 0 && sx < 80) ? xp[sy*80 + sx] : 0.f;
    }
    constexpr int R = (K-1)/2;
    float wr[K*K];
    #pragma unroll
    for (int q = 0; q < K*K; q++) wr[q] = w[c*K*K + q];
    float bv = bias[c];
    __syncthreads();
    float* yp = y + ((size_t)b*256 + ch) * 6400;
    for (int p = threadIdx.x; p < 6400; p += 256) {
        int py = p / 80, px = p - (p/80)*80;
        float acc = bv + tile[(py+4)*88 + (px+4)];       // bias + residual
        #pragma unroll
        for (int ky = 0; ky < K; ky++)
            #pragma unroll
            for (int kx = 0; kx < K; kx++)
                acc = fmaf(wr[ky*K+kx], tile[(py+4-R+ky)*88 + (px+4-R+kx)], acc);
        yp[p] = fmaxf(acc, 0.f);
    }
}

// ---------------------------------------------------------------------------
// Kernel C: per (b, branch): qkv GEMM per token; write qexp = exp(q_raw);
// accumulate qs[h][e] = sum_t exp(q_raw) and ctx[h][ke][vd] = sum_t khat*v.
// grid (25, 16, 4), block 256 = 4 waves, each wave owns 64 tokens (lane = token).
__global__ __launch_bounds__(256) void attn_stats(const float* __restrict__ y,
    const float* __restrict__ wqkv, float* __restrict__ qexp,
    float* __restrict__ ctx, float* __restrict__ qs) {
    int b = blockIdx.y, br = blockIdx.z;
    int lane = threadIdx.x & 63;
    int wv   = threadIdx.x >> 6;
    int t = blockIdx.x*256 + wv*64 + lane;
    __shared__ float ctx_s[512];
    __shared__ float qs_s[64];
    for (int p = threadIdx.x; p < 512; p += 256) ctx_s[p] = 0.f;
    if (threadIdx.x < 64) qs_s[threadIdx.x] = 0.f;
    __syncthreads();

    // load this token's 64-channel vector (coalesced across lanes per channel)
    const float* yp = y + ((size_t)b*256 + br*64) * 6400 + t;
    float yv[64];
    #pragma unroll
    for (int c = 0; c < 64; c++) yv[c] = yp[(size_t)c * 6400];

    size_t qb = ((size_t)(br*16 + b)) * 8 * 51200;   // + h*51200 + t*8 + e
    // ---- q part: exp + materialize + wave-reduce sums
    for (int h = 0; h < 8; h++) {
        #pragma unroll
        for (int e = 0; e < 8; e++) {
            const float* wr = wqkv + (h*8 + e)*64;
            float a0 = 0.f, a1 = 0.f;
            #pragma unroll
            for (int c = 0; c < 32; c++) {
                a0 = fmaf(yv[c],    wr[c],    a0);
                a1 = fmaf(yv[c+32], wr[c+32], a1);
            }
            float qv = __expf(a0 + a1);
            qexp[qb + (size_t)h*51200 + (size_t)t*8 + e] = qv;
            float s = qv;
            #pragma unroll
            for (int off = 32; off; off >>= 1) s += __shfl_xor(s, off);
            if (lane == 0) atomicAdd(&qs_s[h*8 + e], s);
        }
    }
    // ---- k,v part: per-head softmax(k) over 8 dims, outer-product into ctx
    for (int h = 0; h < 8; h++) {
        float kr[8], vr[8];
        #pragma unroll
        for (int e = 0; e < 8; e++) {
            const float* wr = wqkv + (64 + h*8 + e)*64;
            float a0 = 0.f, a1 = 0.f;
            #pragma unroll
            for (int c = 0; c < 32; c++) {
                a0 = fmaf(yv[c],    wr[c],    a0);
                a1 = fmaf(yv[c+32], wr[c+32], a1);
            }
            kr[e] = a0 + a1;
        }
        #pragma unroll
        for (int d = 0; d < 8; d++) {
            const float* wr = wqkv + (128 + h*8 + d)*64;
            float a0 = 0.f, a1 = 0.f;
            #pragma unroll
            for (int c = 0; c < 32; c++) {
                a0 = fmaf(yv[c],    wr[c],    a0);
                a1 = fmaf(yv[c+32], wr[c+32], a1);
            }
            vr[d] = a0 + a1;
        }
        float m = kr[0];
        #pragma unroll
        for (int e = 1; e < 8; e++) m = fmaxf(m, kr[e]);
        float ss = 0.f;
        #pragma unroll
        for (int e = 0; e < 8; e++) { kr[e] = __expf(kr[e] - m); ss += kr[e]; }
        float inv = 1.f / ss;
        #pragma unroll
        for (int e = 0; e < 8; e++) kr[e] *= inv;
        #pragma unroll
        for (int e = 0; e < 8; e++) {
            #pragma unroll
            for (int d = 0; d < 8; d++) {
                float v = kr[e] * vr[d];
                #pragma unroll
                for (int off = 32; off; off >>= 1) v += __shfl_xor(v, off);
                if (lane == 0) atomicAdd(&ctx_s[(h*8 + e)*8 + d], v);
            }
        }
    }
    __syncthreads();
    float* ctxg = ctx + (size_t)(br*16 + b) * 512;
    for (int p = threadIdx.x; p < 512; p += 256) atomicAdd(&ctxg[p], ctx_s[p]);
    if (threadIdx.x < 64)
        atomicAdd(&qs[(size_t)(br*16 + b)*64 + threadIdx.x], qs_s[threadIdx.x]);
}

// ---------------------------------------------------------------------------
// Kernel D: ctxn[g][h][ke][vd] = ctx[...] / qs[g][h][ke]
__global__ void norm_ctx(const float* __restrict__ ctx, const float* __restrict__ qs,
                         float* __restrict__ ctxn) {
    int g = blockIdx.x;       // 64 = i*16+b
    int p = threadIdx.x;      // 512 = h*64 + ke*8 + vd
    ctxn[g*512 + p] = ctx[g*512 + p] / qs[g*64 + (p >> 3)];
}

// ---------------------------------------------------------------------------
// Kernel E: final output.
//   a[pos][i*64 + s*8 + d] = sum_e qexp[i,b,h, g*8+s, e] * ctxn[i,b,h,e,d]
//     with n' = n0+pos, h = n'/800, g = n'%800   (replicates the raw-reshape)
//   out[b][o][n'] = bc[o] + sum_{c=0..255} Wc[o][c] * a[pos][c]
// grid (100, 16), block 256. LDS a_s[64][256] with XOR swizzle (bank-conflict-free).
__global__ __launch_bounds__(256) void final_out(const float* __restrict__ qexp,
    const float* __restrict__ ctxn, const float* __restrict__ Wc,
    const float* __restrict__ bc, float* __restrict__ out) {
    __shared__ float a_s[64][256];
    int b  = blockIdx.y;
    int n0 = blockIdx.x * 64;
    int lane = threadIdx.x & 63;
    int grp  = threadIdx.x >> 6;    // = branch i for phase 1
    int swz  = lane & 31;
    {
        int np = n0 + lane;
        int h = np / 800;
        int g = np - h * 800;
        const float* qe = qexp + (((size_t)(grp*16 + b)*8 + h)*6400 + (size_t)g*8) * 8;
        const float* cx = ctxn + ((size_t)(grp*16 + b)*8 + h) * 64;
        float cxr[64];
        #pragma unroll
        for (int p = 0; p < 64; p++) cxr[p] = cx[p];
        #pragma unroll
        for (int s = 0; s < 8; s++) {
            float qr[8];
            #pragma unroll
            for (int e = 0; e < 8; e++) qr[e] = qe[s*8 + e];
            #pragma unroll
            for (int d = 0; d < 8; d++) {
                float acc = 0.f;
                #pragma unroll
                for (int e = 0; e < 8; e++) acc = fmaf(qr[e], cxr[e*8 + d], acc);
                int ch = grp*64 + s*8 + d;
                a_s[lane][ch ^ swz] = acc;
            }
        }
    }
    __syncthreads();
    float* op = out + (size_t)b * 256 * 6400 + n0 + lane;
    for (int jc = 0; jc < 4; jc++) {
        int ob = grp*64 + jc*16;
        float acc[16];
        #pragma unroll
        for (int j = 0; j < 16; j++) acc[j] = bc[ob + j];
        #pragma unroll 4
        for (int c = 0; c < 256; c++) {
            float av = a_s[lane][c ^ swz];
            #pragma unroll
            for (int j = 0; j < 16; j++)
                acc[j] = fmaf(av, Wc[(ob + j)*256 + c], acc[j]);
        }
        #pragma unroll
        for (int j = 0; j < 16; j++) op[(size_t)(ob + j) * 6400] = acc[j];
    }
}

// ---------------------------------------------------------------------------
extern "C" void kernel_launch(void* const* d_in, const int* in_sizes, int n_in,
                              void* d_out, int out_size, void* d_ws, size_t ws_size,
                              hipStream_t stream) {
    const float* x     = (const float*)d_in[0];
    const float* w3    = (const float*)d_in[1];
    const float* b3    = (const float*)d_in[2];
    const float* w5    = (const float*)d_in[3];
    const float* b5    = (const float*)d_in[4];
    const float* w7    = (const float*)d_in[5];
    const float* b7    = (const float*)d_in[6];
    const float* w9    = (const float*)d_in[7];
    const float* b9    = (const float*)d_in[8];
    const float* wqkv  = (const float*)d_in[9];
    const float* wproj = (const float*)d_in[10];
    const float* bproj = (const float*)d_in[11];
    const float* wf    = (const float*)d_in[12];
    const float* bf    = (const float*)d_in[13];
    const float* scale = (const float*)d_in[14];
    float* out = (float*)d_out;
    float* ws  = (float*)d_ws;

    // zero the atomic accumulators (ctx + qs, contiguous)
    hipMemsetAsync(ws + OFF_CTX, 0, (32768 + 4096) * sizeof(float), stream);

    combine_w<<<256, 64, 0, stream>>>(wf, wproj, bproj, bf, scale,
                                      ws + OFF_WC, ws + OFF_BC);

    dwconv_k<3><<<1024, 256, 0, stream>>>(x, w3, b3, ws + OFF_Y, 0);
    dwconv_k<5><<<1024, 256, 0, stream>>>(x, w5, b5, ws + OFF_Y, 1);
    dwconv_k<7><<<1024, 256, 0, stream>>>(x, w7, b7, ws + OFF_Y, 2);
    dwconv_k<9><<<1024, 256, 0, stream>>>(x, w9, b9, ws + OFF_Y, 3);

    attn_stats<<<dim3(25, 16, 4), 256, 0, stream>>>(ws + OFF_Y, wqkv,
        ws + OFF_QEXP, ws + OFF_CTX, ws + OFF_QS);

    norm_ctx<<<64, 512, 0, stream>>>(ws + OFF_CTX, ws + OFF_QS, ws + OFF_CTXN);

    final_out<<<dim3(100, 16), 256, 0, stream>>>(ws + OFF_QEXP, ws + OFF_CTXN,
        ws + OFF_WC, ws + OFF_BC, out);
}

// Round 2
// 884.809 us; speedup vs baseline: 2.0652x; 2.0652x over previous
//
#include <hip/hip_runtime.h>
#include <hip/hip_bf16.h>
#include <cstddef>
#include <cstdint>

// Problem constants: B=16, DIM=256, H=W=80, C=64/branch, HEADS=8, DH=8, n=6400
// Workspace layout (float offsets):
static constexpr size_t OFF_Y    = 0;                    // [b][256][6400]
static constexpr size_t OFF_QEXP = 26214400;             // [i][b][h][t][e]
static constexpr size_t OFF_CTX  = 52428800;             // [i*16+b][h][ke][vd]
static constexpr size_t OFF_QS   = 52461568;             // [i*16+b][h][e]
static constexpr size_t OFF_CTXN = 52465664;             // normalized ctx
static constexpr size_t OFF_WCT  = 52498432;             // combined weight transposed [256 c][256 o]
static constexpr size_t OFF_BC   = 52563968;             // combined bias [256]

// ---------------------------------------------------------------------------
// Kernel A: fold wproj/scale/wf/bproj/bf into WcT[c][o] (transposed!), bc[o]
//   WcT[i*64+c'][o] = scale[i] * sum_cc wf[o, i*64+cc] * wproj[cc, c']
__global__ void combine_w(const float* __restrict__ wf, const float* __restrict__ wproj,
                          const float* __restrict__ bproj, const float* __restrict__ bf,
                          const float* __restrict__ scale,
                          float* __restrict__ WcT, float* __restrict__ bc) {
    int o  = blockIdx.x;     // 256
    int cp = threadIdx.x;    // 64
    for (int i = 0; i < 4; i++) {
        float s = 0.f;
        for (int cc = 0; cc < 64; cc++)
            s = fmaf(wf[o*256 + i*64 + cc], wproj[cc*64 + cp], s);
        WcT[(i*64 + cp)*256 + o] = scale[i] * s;
    }
    if (cp == 0) {
        float s = bf[o];
        for (int i = 0; i < 4; i++) {
            float t = 0.f;
            for (int cc = 0; cc < 64; cc++)
                t = fmaf(wf[o*256 + i*64 + cc], bproj[cc], t);
            s = fmaf(scale[i], t, s);
        }
        bc[o] = s;
    }
}

// ---------------------------------------------------------------------------
// Kernel B: depthwise conv KxK SAME + bias + residual + relu (templated on K)
template<int K>
__global__ __launch_bounds__(256) void dwconv_k(const float* __restrict__ x,
    const float* __restrict__ w, const float* __restrict__ bias,
    float* __restrict__ y, int br) {
    __shared__ float tile[88*88];
    int b = blockIdx.x >> 6;
    int c = blockIdx.x & 63;
    int ch = br*64 + c;
    const float* xp = x + ((size_t)b*256 + ch) * 6400;
    for (int p = threadIdx.x; p < 88*88; p += 256) {
        int ty = p / 88, tx = p - (p/88)*88;
        int sy = ty - 4, sx = tx - 4;
        tile[p] = (sy >= 0 && sy < 80 && sx >= 0 && sx < 80) ? xp[sy*80 + sx] : 0.f;
    }
    constexpr int R = (K-1)/2;
    float wr[K*K];
    #pragma unroll
    for (int q = 0; q < K*K; q++) wr[q] = w[c*K*K + q];
    float bv = bias[c];
    __syncthreads();
    float* yp = y + ((size_t)b*256 + ch) * 6400;
    for (int p = threadIdx.x; p < 6400; p += 256) {
        int py = p / 80, px = p - (p/80)*80;
        float acc = bv + tile[(py+4)*88 + (px+4)];       // bias + residual
        #pragma unroll
        for (int ky = 0; ky < K; ky++)
            #pragma unroll
            for (int kx = 0; kx < K; kx++)
                acc = fmaf(wr[ky*K+kx], tile[(py+4-R+ky)*88 + (px+4-R+kx)], acc);
        yp[p] = fmaxf(acc, 0.f);
    }
}

// ---------------------------------------------------------------------------
// Kernel C v2: wave = one head. Weights staged in LDS, read as wave-uniform
// b128 broadcasts shared across 2 tokens/lane. ctx/qs accumulate in registers
// across 10 tokens/lane; single butterfly reduce + atomics at the end.
// grid (10, 16, 4), block 512 = 8 waves (= 8 heads). 640 tokens per block.
__global__ __launch_bounds__(512) void attn_stats(const float* __restrict__ y,
    const float* __restrict__ wqkv, float* __restrict__ qexp,
    float* __restrict__ ctx, float* __restrict__ qs) {
    __shared__ float4 w_s[192*16];       // wqkv rows as float4 chunks (48 KB)
    int b = blockIdx.y, br = blockIdx.z;
    int h    = threadIdx.x >> 6;
    int lane = threadIdx.x & 63;
    const float4* wg = (const float4*)wqkv;
    for (int p = threadIdx.x; p < 192*16; p += 512) w_s[p] = wg[p];
    __syncthreads();

    const float* yp = y + ((size_t)b*256 + br*64) * 6400;
    size_t qb = (size_t)(br*16 + b) * 8 * 51200 + (size_t)h * 51200;
    float ctx_l[64], qs_l[8];
    #pragma unroll
    for (int j = 0; j < 64; j++) ctx_l[j] = 0.f;
    #pragma unroll
    for (int e = 0; e < 8; e++) qs_l[e] = 0.f;

    int t0 = blockIdx.x * 640;
    int rq = h*8, rk = 64 + h*8, rv = 128 + h*8;

    for (int it = 0; it < 5; it++) {
        int tA = t0 + it*128 + lane;
        int tB = tA + 64;
        float accA[24], accB[24];
        #pragma unroll
        for (int r = 0; r < 24; r++) { accA[r] = 0.f; accB[r] = 0.f; }
        #pragma unroll 4
        for (int c4 = 0; c4 < 64; c4 += 4) {
            int cq = c4 >> 2;
            float yA0 = yp[(size_t)(c4+0)*6400 + tA];
            float yA1 = yp[(size_t)(c4+1)*6400 + tA];
            float yA2 = yp[(size_t)(c4+2)*6400 + tA];
            float yA3 = yp[(size_t)(c4+3)*6400 + tA];
            float yB0 = yp[(size_t)(c4+0)*6400 + tB];
            float yB1 = yp[(size_t)(c4+1)*6400 + tB];
            float yB2 = yp[(size_t)(c4+2)*6400 + tB];
            float yB3 = yp[(size_t)(c4+3)*6400 + tB];
            #pragma unroll
            for (int e = 0; e < 8; e++) {
                float4 w = w_s[(rq+e)*16 + cq];
                accA[e] = fmaf(w.x,yA0, fmaf(w.y,yA1, fmaf(w.z,yA2, fmaf(w.w,yA3, accA[e]))));
                accB[e] = fmaf(w.x,yB0, fmaf(w.y,yB1, fmaf(w.z,yB2, fmaf(w.w,yB3, accB[e]))));
            }
            #pragma unroll
            for (int e = 0; e < 8; e++) {
                float4 w = w_s[(rk+e)*16 + cq];
                accA[8+e] = fmaf(w.x,yA0, fmaf(w.y,yA1, fmaf(w.z,yA2, fmaf(w.w,yA3, accA[8+e]))));
                accB[8+e] = fmaf(w.x,yB0, fmaf(w.y,yB1, fmaf(w.z,yB2, fmaf(w.w,yB3, accB[8+e]))));
            }
            #pragma unroll
            for (int e = 0; e < 8; e++) {
                float4 w = w_s[(rv+e)*16 + cq];
                accA[16+e] = fmaf(w.x,yA0, fmaf(w.y,yA1, fmaf(w.z,yA2, fmaf(w.w,yA3, accA[16+e]))));
                accB[16+e] = fmaf(w.x,yB0, fmaf(w.y,yB1, fmaf(w.z,yB2, fmaf(w.w,yB3, accB[16+e]))));
            }
        }
        // epilogue per token
        #pragma unroll
        for (int tok = 0; tok < 2; tok++) {
            float* acc = tok ? accB : accA;
            int t = tok ? tB : tA;
            // q: exp, store, accumulate sums
            float q0 = __expf(acc[0]), q1 = __expf(acc[1]);
            float q2 = __expf(acc[2]), q3 = __expf(acc[3]);
            float q4 = __expf(acc[4]), q5 = __expf(acc[5]);
            float q6 = __expf(acc[6]), q7 = __expf(acc[7]);
            qs_l[0] += q0; qs_l[1] += q1; qs_l[2] += q2; qs_l[3] += q3;
            qs_l[4] += q4; qs_l[5] += q5; qs_l[6] += q6; qs_l[7] += q7;
            float4* qo = (float4*)(qexp + qb + (size_t)t*8);
            qo[0] = make_float4(q0,q1,q2,q3);
            qo[1] = make_float4(q4,q5,q6,q7);
            // k softmax over 8 dims
            float kr[8], vr[8];
            #pragma unroll
            for (int e = 0; e < 8; e++) { kr[e] = acc[8+e]; vr[e] = acc[16+e]; }
            float m = kr[0];
            #pragma unroll
            for (int e = 1; e < 8; e++) m = fmaxf(m, kr[e]);
            float ss = 0.f;
            #pragma unroll
            for (int e = 0; e < 8; e++) { kr[e] = __expf(kr[e] - m); ss += kr[e]; }
            float inv = 1.f / ss;
            #pragma unroll
            for (int e = 0; e < 8; e++) kr[e] *= inv;
            #pragma unroll
            for (int e = 0; e < 8; e++)
                #pragma unroll
                for (int d = 0; d < 8; d++)
                    ctx_l[e*8+d] = fmaf(kr[e], vr[d], ctx_l[e*8+d]);
        }
    }
    // reduce ctx_l across the wave; lane j commits element j
    float* ctxg = ctx + (size_t)(br*16 + b) * 512 + h*64;
    #pragma unroll
    for (int j = 0; j < 64; j++) {
        float v = ctx_l[j];
        #pragma unroll
        for (int off = 32; off; off >>= 1) v += __shfl_xor(v, off);
        if (lane == j) atomicAdd(&ctxg[j], v);
    }
    float* qsg = qs + (size_t)(br*16 + b) * 64 + h*8;
    #pragma unroll
    for (int j = 0; j < 8; j++) {
        float v = qs_l[j];
        #pragma unroll
        for (int off = 32; off; off >>= 1) v += __shfl_xor(v, off);
        if (lane == j) atomicAdd(&qsg[j], v);
    }
}

// ---------------------------------------------------------------------------
// Kernel D: ctxn = ctx / qs
__global__ void norm_ctx(const float* __restrict__ ctx, const float* __restrict__ qs,
                         float* __restrict__ ctxn) {
    int g = blockIdx.x;       // 64 = i*16+b
    int p = threadIdx.x;      // 512 = h*64 + ke*8 + vd
    ctxn[g*512 + p] = ctx[g*512 + p] / qs[g*64 + (p >> 3)];
}

// ---------------------------------------------------------------------------
// Kernel E v2: a staged transposed in LDS a_s[c][pos] (pad 68, conflict-free
// b128 reads); WcT read as float4 (L2-resident); register tile 4 pos x 16 out.
// grid (100, 16), block 256.
__global__ __launch_bounds__(256) void final_out(const float* __restrict__ qexp,
    const float* __restrict__ ctxn, const float* __restrict__ WcT,
    const float* __restrict__ bc, float* __restrict__ out) {
    __shared__ float a_s[256][68];
    int b  = blockIdx.y;
    int n0 = blockIdx.x * 64;
    int lane = threadIdx.x & 63;
    int grp  = threadIdx.x >> 6;    // = branch i for phase 1
    {
        int np = n0 + lane;
        int h = np / 800;
        int g = np - h * 800;
        const float* qe = qexp + ((size_t)(grp*16 + b)*8 + h)*51200 + (size_t)g*64;
        const float* cx = ctxn + ((size_t)(grp*16 + b)*8 + h)*64;
        float cxr[64];
        #pragma unroll
        for (int p = 0; p < 64; p++) cxr[p] = cx[p];
        #pragma unroll
        for (int s = 0; s < 8; s++) {
            float qr[8];
            #pragma unroll
            for (int e = 0; e < 8; e++) qr[e] = qe[s*8 + e];
            #pragma unroll
            for (int d = 0; d < 8; d++) {
                float acc = 0.f;
                #pragma unroll
                for (int e = 0; e < 8; e++) acc = fmaf(qr[e], cxr[e*8 + d], acc);
                a_s[grp*64 + s*8 + d][lane] = acc;
            }
        }
    }
    __syncthreads();
    int j0 = (threadIdx.x >> 4) * 16;   // output group (16 outs)
    int p0 = (threadIdx.x & 15) * 4;    // position group (4 pos)
    float acc[4][16];
    #pragma unroll
    for (int j = 0; j < 16; j++) {
        float bv = bc[j0 + j];
        acc[0][j] = bv; acc[1][j] = bv; acc[2][j] = bv; acc[3][j] = bv;
    }
    const float4* wt = (const float4*)WcT;
    int wj = j0 >> 2;
    #pragma unroll 2
    for (int c = 0; c < 256; c++) {
        float4 a4 = *(const float4*)&a_s[c][p0];
        float4 w0 = wt[c*64 + wj + 0];
        float4 w1 = wt[c*64 + wj + 1];
        float4 w2 = wt[c*64 + wj + 2];
        float4 w3 = wt[c*64 + wj + 3];
        float wv[16] = {w0.x,w0.y,w0.z,w0.w, w1.x,w1.y,w1.z,w1.w,
                        w2.x,w2.y,w2.z,w2.w, w3.x,w3.y,w3.z,w3.w};
        float av[4] = {a4.x, a4.y, a4.z, a4.w};
        #pragma unroll
        for (int i = 0; i < 4; i++)
            #pragma unroll
            for (int j = 0; j < 16; j++)
                acc[i][j] = fmaf(av[i], wv[j], acc[i][j]);
    }
    float* op = out + (size_t)b * 256 * 6400 + (size_t)(n0 + p0);
    #pragma unroll
    for (int j = 0; j < 16; j++) {
        float4 o4 = make_float4(acc[0][j], acc[1][j], acc[2][j], acc[3][j]);
        *(float4*)&op[(size_t)(j0 + j) * 6400] = o4;
    }
}

// ---------------------------------------------------------------------------
extern "C" void kernel_launch(void* const* d_in, const int* in_sizes, int n_in,
                              void* d_out, int out_size, void* d_ws, size_t ws_size,
                              hipStream_t stream) {
    const float* x     = (const float*)d_in[0];
    const float* w3    = (const float*)d_in[1];
    const float* b3    = (const float*)d_in[2];
    const float* w5    = (const float*)d_in[3];
    const float* b5    = (const float*)d_in[4];
    const float* w7    = (const float*)d_in[5];
    const float* b7    = (const float*)d_in[6];
    const float* w9    = (const float*)d_in[7];
    const float* b9    = (const float*)d_in[8];
    const float* wqkv  = (const float*)d_in[9];
    const float* wproj = (const float*)d_in[10];
    const float* bproj = (const float*)d_in[11];
    const float* wf    = (const float*)d_in[12];
    const float* bf    = (const float*)d_in[13];
    const float* scale = (const float*)d_in[14];
    float* out = (float*)d_out;
    float* ws  = (float*)d_ws;

    // zero the atomic accumulators (ctx + qs, contiguous)
    hipMemsetAsync(ws + OFF_CTX, 0, (32768 + 4096) * sizeof(float), stream);

    combine_w<<<256, 64, 0, stream>>>(wf, wproj, bproj, bf, scale,
                                      ws + OFF_WCT, ws + OFF_BC);

    dwconv_k<3><<<1024, 256, 0, stream>>>(x, w3, b3, ws + OFF_Y, 0);
    dwconv_k<5><<<1024, 256, 0, stream>>>(x, w5, b5, ws + OFF_Y, 1);
    dwconv_k<7><<<1024, 256, 0, stream>>>(x, w7, b7, ws + OFF_Y, 2);
    dwconv_k<9><<<1024, 256, 0, stream>>>(x, w9, b9, ws + OFF_Y, 3);

    attn_stats<<<dim3(10, 16, 4), 512, 0, stream>>>(ws + OFF_Y, wqkv,
        ws + OFF_QEXP, ws + OFF_CTX, ws + OFF_QS);

    norm_ctx<<<64, 512, 0, stream>>>(ws + OFF_CTX, ws + OFF_QS, ws + OFF_CTXN);

    final_out<<<dim3(100, 16), 256, 0, stream>>>(ws + OFF_QEXP, ws + OFF_CTXN,
        ws + OFF_WCT, ws + OFF_BC, out);
}

// Round 3
// 568.550 us; speedup vs baseline: 3.2140x; 1.5563x over previous
//
#include <hip/hip_runtime.h>
#include <hip/hip_bf16.h>
#include <cstddef>
#include <cstdint>

// Problem constants: B=16, DIM=256, H=W=80, C=64/branch, HEADS=8, DH=8, n=6400
typedef __attribute__((ext_vector_type(8))) short short8;
typedef __attribute__((ext_vector_type(4))) float f32x4;
typedef unsigned short ushortT;

// Workspace layout (float offsets):
static constexpr size_t OFF_Y    = 0;          // y fp32 [16][256][6400]
static constexpr size_t OFF_QEXP = 26214400;   // qexp [i][b][h][t][e] fp32
static constexpr size_t OFF_CTX  = 52428800;   // ctx [i*16+b][h][e][d] fp32 (32768)
static constexpr size_t OFF_QS   = 52461568;   // qs  [i*16+b][h][e]    fp32 (4096)
static constexpr size_t OFF_WCF  = 52465664;   // wc frags  [16mt][8ks][64][8] bf16 (65536 u16)
static constexpr size_t OFF_WQF  = 52498432;   // wqkv frags [12rt][2ks][64][8] bf16 (12288 u16)
static constexpr size_t OFF_BC   = 52504576;   // bc [256] fp32

__device__ inline ushortT f2bf(float f) {
    __hip_bfloat16 h = __float2bfloat16(f);
    return *reinterpret_cast<ushortT*>(&h);
}
__device__ inline float bf2f(ushortT u) {
    __hip_bfloat16 h = *reinterpret_cast<__hip_bfloat16*>(&u);
    return __bfloat162float(h);
}

// ---------------------------------------------------------------------------
// Pack wqkv into MFMA A-fragment order (single bf16):
// wqf[((rt*2+ks)*64+lane)*8+i] = bf16(wqkv[rt*16+(lane&15)][ks*32+((lane>>4)&3)*8+i])
__global__ void pack_wq(const float* __restrict__ wqkv, ushortT* __restrict__ wqf) {
    int idx = blockIdx.x * 256 + threadIdx.x;
    if (idx < 12288) {
        int i = idx & 7, ln = (idx >> 3) & 63, kk = idx >> 9;
        int rt = kk >> 1, ks = kk & 1;
        int row = rt * 16 + (ln & 15), col = ks * 32 + ((ln >> 4) & 3) * 8 + i;
        wqf[idx] = f2bf(wqkv[row * 64 + col]);
    }
}

// ---------------------------------------------------------------------------
// Fold wproj/scale/wf into combined weight, written DIRECTLY as bf16 MFMA
// A-fragments: Wc[o][i*64+cc] = scale[i]*sum_c' wf[o][i*64+c']*wproj[c'][cc]
__global__ void combine_w(const float* __restrict__ wf, const float* __restrict__ wproj,
                          const float* __restrict__ bproj, const float* __restrict__ bf,
                          const float* __restrict__ scale,
                          ushortT* __restrict__ wcf, float* __restrict__ bc) {
    int o  = blockIdx.x;     // 256
    int cp = threadIdx.x;    // 64
    for (int i = 0; i < 4; i++) {
        float s = 0.f;
        for (int d = 0; d < 64; d++)
            s = fmaf(wf[o * 256 + i * 64 + d], wproj[d * 64 + cp], s);
        s *= scale[i];
        int col = i * 64 + cp;
        int mt = o >> 4, ks = col >> 5, ln = (o & 15) | (((col >> 3) & 3) << 4), ii = col & 7;
        wcf[((mt * 8 + ks) * 64 + ln) * 8 + ii] = f2bf(s);
    }
    if (cp == 0) {
        float s = bf[o];
        for (int i = 0; i < 4; i++) {
            float t = 0.f;
            for (int d = 0; d < 64; d++)
                t = fmaf(wf[o * 256 + i * 64 + d], bproj[d], t);
            s = fmaf(scale[i], t, s);
        }
        bc[o] = s;
    }
}

// ---------------------------------------------------------------------------
// Kernel B: depthwise conv KxK SAME + bias + residual + relu (unchanged)
template<int K>
__global__ __launch_bounds__(256) void dwconv_k(const float* __restrict__ x,
    const float* __restrict__ w, const float* __restrict__ bias,
    float* __restrict__ y, int br) {
    __shared__ float tile[88 * 88];
    int b = blockIdx.x >> 6;
    int c = blockIdx.x & 63;
    int ch = br * 64 + c;
    const float* xp = x + ((size_t)b * 256 + ch) * 6400;
    for (int p = threadIdx.x; p < 88 * 88; p += 256) {
        int ty = p / 88, tx = p - (p / 88) * 88;
        int sy = ty - 4, sx = tx - 4;
        tile[p] = (sy >= 0 && sy < 80 && sx >= 0 && sx < 80) ? xp[sy * 80 + sx] : 0.f;
    }
    constexpr int R = (K - 1) / 2;
    float wr[K * K];
    #pragma unroll
    for (int q = 0; q < K * K; q++) wr[q] = w[c * K * K + q];
    float bv = bias[c];
    __syncthreads();
    float* yp = y + ((size_t)b * 256 + ch) * 6400;
    for (int p = threadIdx.x; p < 6400; p += 256) {
        int py = p / 80, px = p - (p / 80) * 80;
        float acc = bv + tile[(py + 4) * 88 + (px + 4)];
        #pragma unroll
        for (int ky = 0; ky < K; ky++)
            #pragma unroll
            for (int kx = 0; kx < K; kx++)
                acc = fmaf(wr[ky * K + kx], tile[(py + 4 - R + ky) * 88 + (px + 4 - R + kx)], acc);
        yp[p] = fmaxf(acc, 0.f);
    }
}

// ---------------------------------------------------------------------------
// Kernel C v3: MFMA qkv GEMM + fused stats.
// grid (25, 16, 4), block 256 = 4 waves; wave owns 64 tokens (2 passes of 32).
// C rows = qkv rows (A = W frags, L2 global), C cols = tokens (B = y hi/lo).
__global__ __launch_bounds__(256) void attn_stats(const float* __restrict__ y,
    const ushortT* __restrict__ wqf, float* __restrict__ qexp,
    float* __restrict__ ctx, float* __restrict__ qs) {
    __shared__ ushortT kv_s[4][32][136];   // per wave: [t][0..63]=k/khat, [64..127]=v
    int b = blockIdx.y, br = blockIdx.z;
    int w = threadIdx.x >> 6, lane = threadIdx.x & 63;
    int g = lane >> 4, c = lane & 15;
    int t0 = blockIdx.x * 256 + w * 64;
    const float* yb = y + ((size_t)b * 256 + br * 64) * 6400;
    size_t qb = (size_t)(br * 16 + b) * 409600;
    float* qsg = qs + (size_t)(br * 16 + b) * 64;
    float cacc[8];
    #pragma unroll
    for (int d = 0; d < 8; d++) cacc[d] = 0.f;
    const short8* wfp = (const short8*)wqf;

    for (int p = 0; p < 2; p++) {
        // ---- build B-frags (y hi/lo) for 32 tokens
        short8 byh[2][2], byl[2][2];
        #pragma unroll
        for (int tt = 0; tt < 2; tt++)
            #pragma unroll
            for (int ks = 0; ks < 2; ks++) {
                int t = t0 + p * 32 + tt * 16 + c;
                int c0 = ks * 32 + g * 8;
                short8 hi, lo;
                #pragma unroll
                for (int i = 0; i < 8; i++) {
                    float v = yb[(size_t)(c0 + i) * 6400 + t];
                    ushortT hb = f2bf(v);
                    hi[i] = (short)hb;
                    lo[i] = (short)f2bf(v - bf2f(hb));
                }
                byh[tt][ks] = hi; byl[tt][ks] = lo;
            }
        // ---- MFMA over 12 row-tiles
        short8 a0 = wfp[0 * 64 + lane];
        short8 a1 = wfp[1 * 64 + lane];
        #pragma unroll
        for (int rt = 0; rt < 12; rt++) {
            short8 na0, na1;
            if (rt < 11) {
                na0 = wfp[((rt + 1) * 2 + 0) * 64 + lane];
                na1 = wfp[((rt + 1) * 2 + 1) * 64 + lane];
            }
            f32x4 acc[2];
            acc[0] = {0.f, 0.f, 0.f, 0.f};
            acc[1] = {0.f, 0.f, 0.f, 0.f};
            #pragma unroll
            for (int tt = 0; tt < 2; tt++) {
                acc[tt] = __builtin_amdgcn_mfma_f32_16x16x32_bf16(a0, byh[tt][0], acc[tt], 0, 0, 0);
                acc[tt] = __builtin_amdgcn_mfma_f32_16x16x32_bf16(a1, byh[tt][1], acc[tt], 0, 0, 0);
                acc[tt] = __builtin_amdgcn_mfma_f32_16x16x32_bf16(a0, byl[tt][0], acc[tt], 0, 0, 0);
                acc[tt] = __builtin_amdgcn_mfma_f32_16x16x32_bf16(a1, byl[tt][1], acc[tt], 0, 0, 0);
            }
            if (rt < 4) {
                // q rows: exp -> store qexp, accumulate qs
                int h = rt * 2 + (g >> 1), e0 = (g & 1) * 4;
                float qsum[4] = {0.f, 0.f, 0.f, 0.f};
                #pragma unroll
                for (int tt = 0; tt < 2; tt++) {
                    int t = t0 + p * 32 + tt * 16 + c;
                    float4 qv;
                    qv.x = __expf(acc[tt][0]); qv.y = __expf(acc[tt][1]);
                    qv.z = __expf(acc[tt][2]); qv.w = __expf(acc[tt][3]);
                    *(float4*)(qexp + qb + (size_t)h * 51200 + (size_t)t * 8 + e0) = qv;
                    qsum[0] += qv.x; qsum[1] += qv.y; qsum[2] += qv.z; qsum[3] += qv.w;
                }
                #pragma unroll
                for (int j = 0; j < 4; j++) {
                    float v = qsum[j];
                    v += __shfl_xor(v, 1); v += __shfl_xor(v, 2);
                    v += __shfl_xor(v, 4); v += __shfl_xor(v, 8);
                    if (c == 0) atomicAdd(&qsg[h * 8 + e0 + j], v);
                }
            } else {
                // k,v rows -> LDS (bf16)
                int kvr0 = (rt - 4) * 16 + g * 4;
                #pragma unroll
                for (int tt = 0; tt < 2; tt++) {
                    int tl = tt * 16 + c;
                    uint2 pk;
                    pk.x = (uint)f2bf(acc[tt][0]) | ((uint)f2bf(acc[tt][1]) << 16);
                    pk.y = (uint)f2bf(acc[tt][2]) | ((uint)f2bf(acc[tt][3]) << 16);
                    *(uint2*)&kv_s[w][tl][kvr0] = pk;
                }
            }
            if (rt < 11) { a0 = na0; a1 = na1; }
        }
        __syncthreads();
        // ---- k softmax (per token, per head): lane = (half, token)
        {
            int tp = lane & 31, hb2 = (lane >> 5) * 4;
            #pragma unroll
            for (int hh = 0; hh < 4; hh++) {
                int h = hb2 + hh;
                ushortT* kp = &kv_s[w][tp][h * 8];
                short8 kraw = *(short8*)kp;
                float kf[8];
                #pragma unroll
                for (int e = 0; e < 8; e++) kf[e] = bf2f((ushortT)kraw[e]);
                float m = kf[0];
                #pragma unroll
                for (int e = 1; e < 8; e++) m = fmaxf(m, kf[e]);
                float ss = 0.f;
                #pragma unroll
                for (int e = 0; e < 8; e++) { kf[e] = __expf(kf[e] - m); ss += kf[e]; }
                float inv = 1.f / ss;
                short8 ko;
                #pragma unroll
                for (int e = 0; e < 8; e++) ko[e] = (short)f2bf(kf[e] * inv);
                *(short8*)kp = ko;
            }
        }
        __syncthreads();
        // ---- ctx accumulation: lane = h*8+e, broadcast-friendly reads
        {
            int h2 = lane >> 3, e2 = lane & 7;
            #pragma unroll 4
            for (int t = 0; t < 32; t++) {
                float kv = bf2f(kv_s[w][t][h2 * 8 + e2]);
                short8 v8 = *(short8*)&kv_s[w][t][64 + h2 * 8];
                #pragma unroll
                for (int d = 0; d < 8; d++)
                    cacc[d] = fmaf(kv, bf2f((ushortT)v8[d]), cacc[d]);
            }
        }
        __syncthreads();
    }
    float* cg = ctx + (size_t)(br * 16 + b) * 512 + lane * 8;
    #pragma unroll
    for (int d = 0; d < 8; d++) atomicAdd(&cg[d], cacc[d]);
}

// ---------------------------------------------------------------------------
// Kernel E v3: per-position gather (a = qexp . ctx/qs) + MFMA 256x256 GEMM.
// grid (100, 16), block 256/4 waves. a staged bf16 hi/lo in LDS [64t][264c].
__global__ __launch_bounds__(256) void final_out(const float* __restrict__ qexp,
    const float* __restrict__ ctx, const float* __restrict__ qs,
    const ushortT* __restrict__ wcf, const float* __restrict__ bc,
    float* __restrict__ out) {
    __shared__ ushortT a_hi[64][264], a_lo[64][264];
    int b = blockIdx.y, n0 = blockIdx.x * 64;
    int w = threadIdx.x >> 6, lane = threadIdx.x & 63;
    // ---- phase 1: build a[c][t] for c in [w*64, w*64+64), t = lane
    {
        int np = n0 + lane;
        int h = np / 800, gg = np - h * 800;
        int slice = w * 16 + b;
        const float* qe = qexp + ((size_t)slice * 8 + h) * 51200 + (size_t)gg * 64;
        const float* cx = ctx + (size_t)slice * 512 + h * 64;
        const float* qv = qs + (size_t)slice * 64 + h * 8;
        float inv[8];
        #pragma unroll
        for (int e = 0; e < 8; e++) inv[e] = 1.f / qv[e];
        float cxr[64];
        #pragma unroll
        for (int q = 0; q < 64; q++) cxr[q] = cx[q] * inv[q >> 3];
        #pragma unroll
        for (int s = 0; s < 8; s++) {
            const float4* q4 = (const float4*)(qe + s * 8);
            float4 qa = q4[0], qb4 = q4[1];
            float qr[8] = {qa.x, qa.y, qa.z, qa.w, qb4.x, qb4.y, qb4.z, qb4.w};
            short8 hi, lo;
            #pragma unroll
            for (int d = 0; d < 8; d++) {
                float a = 0.f;
                #pragma unroll
                for (int e = 0; e < 8; e++) a = fmaf(qr[e], cxr[e * 8 + d], a);
                ushortT hb = f2bf(a);
                hi[d] = (short)hb;
                lo[d] = (short)f2bf(a - bf2f(hb));
            }
            int c0 = w * 64 + s * 8;
            *(short8*)&a_hi[lane][c0] = hi;
            *(short8*)&a_lo[lane][c0] = lo;
        }
    }
    __syncthreads();
    // ---- phase 2: wave w computes output rows [w*64, w*64+64)
    int g = lane >> 4, cc = lane & 15;
    f32x4 acc[4][4];
    #pragma unroll
    for (int m = 0; m < 4; m++)
        #pragma unroll
        for (int tt = 0; tt < 4; tt++) acc[m][tt] = {0.f, 0.f, 0.f, 0.f};
    const short8* wf8 = (const short8*)wcf;
    #pragma unroll 2
    for (int ks = 0; ks < 8; ks++) {
        short8 bh[4], bl[4];
        #pragma unroll
        for (int tt = 0; tt < 4; tt++) {
            int trow = tt * 16 + cc, c0 = ks * 32 + g * 8;
            bh[tt] = *(const short8*)&a_hi[trow][c0];
            bl[tt] = *(const short8*)&a_lo[trow][c0];
        }
        #pragma unroll
        for (int m = 0; m < 4; m++) {
            short8 aw = wf8[((size_t)(w * 4 + m) * 8 + ks) * 64 + lane];
            #pragma unroll
            for (int tt = 0; tt < 4; tt++) {
                acc[m][tt] = __builtin_amdgcn_mfma_f32_16x16x32_bf16(aw, bh[tt], acc[m][tt], 0, 0, 0);
                acc[m][tt] = __builtin_amdgcn_mfma_f32_16x16x32_bf16(aw, bl[tt], acc[m][tt], 0, 0, 0);
            }
        }
    }
    // ---- store with bias
    float* ob = out + (size_t)b * 256 * 6400 + n0;
    #pragma unroll
    for (int m = 0; m < 4; m++) {
        int o0 = (w * 4 + m) * 16 + g * 4;
        float bcv[4] = {bc[o0], bc[o0 + 1], bc[o0 + 2], bc[o0 + 3]};
        #pragma unroll
        for (int tt = 0; tt < 4; tt++) {
            int t = tt * 16 + cc;
            #pragma unroll
            for (int j = 0; j < 4; j++)
                ob[(size_t)(o0 + j) * 6400 + t] = acc[m][tt][j] + bcv[j];
        }
    }
}

// ---------------------------------------------------------------------------
extern "C" void kernel_launch(void* const* d_in, const int* in_sizes, int n_in,
                              void* d_out, int out_size, void* d_ws, size_t ws_size,
                              hipStream_t stream) {
    const float* x     = (const float*)d_in[0];
    const float* w3    = (const float*)d_in[1];
    const float* b3    = (const float*)d_in[2];
    const float* w5    = (const float*)d_in[3];
    const float* b5    = (const float*)d_in[4];
    const float* w7    = (const float*)d_in[5];
    const float* b7    = (const float*)d_in[6];
    const float* w9    = (const float*)d_in[7];
    const float* b9    = (const float*)d_in[8];
    const float* wqkv  = (const float*)d_in[9];
    const float* wproj = (const float*)d_in[10];
    const float* bproj = (const float*)d_in[11];
    const float* wf    = (const float*)d_in[12];
    const float* bf    = (const float*)d_in[13];
    const float* scale = (const float*)d_in[14];
    float* out = (float*)d_out;
    float* ws  = (float*)d_ws;

    hipMemsetAsync(ws + OFF_CTX, 0, (32768 + 4096) * sizeof(float), stream);

    pack_wq<<<48, 256, 0, stream>>>(wqkv, (ushortT*)(ws + OFF_WQF));
    combine_w<<<256, 64, 0, stream>>>(wf, wproj, bproj, bf, scale,
                                      (ushortT*)(ws + OFF_WCF), ws + OFF_BC);

    dwconv_k<3><<<1024, 256, 0, stream>>>(x, w3, b3, ws + OFF_Y, 0);
    dwconv_k<5><<<1024, 256, 0, stream>>>(x, w5, b5, ws + OFF_Y, 1);
    dwconv_k<7><<<1024, 256, 0, stream>>>(x, w7, b7, ws + OFF_Y, 2);
    dwconv_k<9><<<1024, 256, 0, stream>>>(x, w9, b9, ws + OFF_Y, 3);

    attn_stats<<<dim3(25, 16, 4), 256, 0, stream>>>(ws + OFF_Y,
        (const ushortT*)(ws + OFF_WQF), ws + OFF_QEXP, ws + OFF_CTX, ws + OFF_QS);

    final_out<<<dim3(100, 16), 256, 0, stream>>>(ws + OFF_QEXP, ws + OFF_CTX,
        ws + OFF_QS, (const ushortT*)(ws + OFF_WCF), ws + OFF_BC, out);
}